// Round 1
// baseline (1398.505 us; speedup 1.0000x reference)
//
#include <hip/hip_runtime.h>

// ESIM layer: out = softmax((x@W + b) @ y^T) @ y
// B=64, Sx=Sy=512, D=1024, fp32 in/out.
// K1: proj = x@W+b -> written to d_out (reused as scratch; exactly out-sized).
// K2: per (batch, 64-row sx tile): S=proj@y^T (split-bf16 3-term MFMA),
//     softmax in regs, P->LDS bf16, O=P@y, overwrite own proj rows with O.

typedef float  f32x4  __attribute__((ext_vector_type(4)));
typedef __bf16 bf16x8 __attribute__((ext_vector_type(8)));
typedef __bf16 bf16x4 __attribute__((ext_vector_type(4)));

#define MFMA16(a, b, c) __builtin_amdgcn_mfma_f32_16x16x32_bf16((a), (b), (c), 0, 0, 0)

__device__ __forceinline__ void cvt4(const float4 v, bf16x4& h, bf16x4& l) {
    const float f0 = v.x, f1 = v.y, f2 = v.z, f3 = v.w;
    const __bf16 h0 = (__bf16)f0, h1 = (__bf16)f1, h2 = (__bf16)f2, h3 = (__bf16)f3;
    h = (bf16x4){h0, h1, h2, h3};
    l = (bf16x4){(__bf16)(f0 - (float)h0), (__bf16)(f1 - (float)h1),
                 (__bf16)(f2 - (float)h2), (__bf16)(f3 - (float)h3)};
}

// ------------------------- K1: proj = x@W + b -------------------------------
// M=32768, N=1024, K=1024. 128x128 tile, BK=32, 4 waves (2x2 of 64x64 each).
__global__ __launch_bounds__(256, 2)
void proj_kernel(const float* __restrict__ x, const float* __restrict__ W,
                 const float* __restrict__ bias, float* __restrict__ proj)
{
    __shared__ __bf16 Ah[128][40];  // stride 40 (80B): keeps b128 16B-aligned
    __shared__ __bf16 Al[128][40];
    __shared__ __bf16 Bh[128][40];  // [n][k] (W transposed at staging)
    __shared__ __bf16 Bl[128][40];

    const int tid  = threadIdx.x;
    const int lane = tid & 63;
    const int wave = tid >> 6;
    const int wm   = (wave >> 1) * 64;
    const int wn   = (wave & 1) * 64;
    const int m0   = (blockIdx.x >> 3) * 128;
    const int n0   = (blockIdx.x & 7) * 128;

    const int ar = lane & 15;            // A/B fragment row (m or n)
    const int ak = (lane >> 4) * 8;      // fragment k offset

    f32x4 acc[4][4];
    #pragma unroll
    for (int i = 0; i < 4; ++i)
        #pragma unroll
        for (int j = 0; j < 4; ++j)
            acc[i][j] = (f32x4){0.f, 0.f, 0.f, 0.f};

    const int xr  = tid >> 3;            // x stage: 8 threads/row
    const int xc  = (tid & 7) * 4;
    const int wkb = tid >> 5;            // W stage: 4x4 micro-transpose
    const int wn4 = (tid & 31) * 4;

    for (int k0 = 0; k0 < 1024; k0 += 32) {
        __syncthreads();
        // stage x tile (128x32), k-contiguous, hi+lo split
        #pragma unroll
        for (int it = 0; it < 4; ++it) {
            const int r = xr + it * 32;
            const float4 v = *(const float4*)&x[(size_t)(m0 + r) * 1024 + k0 + xc];
            bf16x4 h, l; cvt4(v, h, l);
            *(bf16x4*)&Ah[r][xc] = h;
            *(bf16x4*)&Al[r][xc] = l;
        }
        // stage W tile (32x128) transposed to [n][k] via 4x4 micro-transpose
        {
            const size_t wb = (size_t)(k0 + wkb * 4) * 1024 + n0 + wn4;
            const float4 v0 = *(const float4*)&W[wb];
            const float4 v1 = *(const float4*)&W[wb + 1024];
            const float4 v2 = *(const float4*)&W[wb + 2048];
            const float4 v3 = *(const float4*)&W[wb + 3072];
            const float rv[4][4] = {{v0.x, v0.y, v0.z, v0.w},
                                    {v1.x, v1.y, v1.z, v1.w},
                                    {v2.x, v2.y, v2.z, v2.w},
                                    {v3.x, v3.y, v3.z, v3.w}};
            #pragma unroll
            for (int j = 0; j < 4; ++j) {
                bf16x4 h, l;
                #pragma unroll
                for (int kk = 0; kk < 4; ++kk) {
                    const float f = rv[kk][j];
                    const __bf16 hb = (__bf16)f;
                    h[kk] = hb;
                    l[kk] = (__bf16)(f - (float)hb);
                }
                *(bf16x4*)&Bh[wn4 + j][wkb * 4] = h;
                *(bf16x4*)&Bl[wn4 + j][wkb * 4] = l;
            }
        }
        __syncthreads();

        bf16x8 a_h[4], a_l[4], b_h[4], b_l[4];
        #pragma unroll
        for (int f = 0; f < 4; ++f) {
            a_h[f] = *(const bf16x8*)&Ah[wm + f * 16 + ar][ak];
            a_l[f] = *(const bf16x8*)&Al[wm + f * 16 + ar][ak];
            b_h[f] = *(const bf16x8*)&Bh[wn + f * 16 + ar][ak];
            b_l[f] = *(const bf16x8*)&Bl[wn + f * 16 + ar][ak];
        }
        #pragma unroll
        for (int i = 0; i < 4; ++i)
            #pragma unroll
            for (int j = 0; j < 4; ++j) {
                acc[i][j] = MFMA16(a_h[i], b_h[j], acc[i][j]);
                acc[i][j] = MFMA16(a_l[i], b_h[j], acc[i][j]);
                acc[i][j] = MFMA16(a_h[i], b_l[j], acc[i][j]);
            }
    }

    // epilogue: +bias, fp32 store. C/D: col=lane&15, row=(lane>>4)*4+reg
    const int q4 = (lane >> 4) * 4;
    #pragma unroll
    for (int j = 0; j < 4; ++j) {
        const int n = n0 + wn + j * 16 + ar;
        const float bv = bias[n];
        #pragma unroll
        for (int i = 0; i < 4; ++i) {
            const size_t base = (size_t)(m0 + wm + i * 16 + q4) * 1024 + n;
            #pragma unroll
            for (int r = 0; r < 4; ++r)
                proj[base + (size_t)r * 1024] = acc[i][j][r] + bv;
        }
    }
}

// ------------------- K2: attention per (batch, 64-row sx tile) --------------
__global__ __launch_bounds__(256, 1)
void attn_kernel(const float* __restrict__ y, float* __restrict__ out)
{
    __shared__ __bf16 Ph[64][40];
    __shared__ __bf16 Pl[64][40];
    __shared__ __bf16 Yh[128][40];
    __shared__ __bf16 Yl[128][40];
    __shared__ __bf16 Pbuf[64][520];   // softmax probs, bf16, padded stride

    const int tid  = threadIdx.x;
    const int lane = tid & 63;
    const int wave = tid >> 6;         // wave owns 16 sx rows
    const int b    = blockIdx.x >> 3;
    const int sx0  = (blockIdx.x & 7) * 64;
    const size_t ybase = (size_t)b * 512 * 1024;
    const size_t pbase = ((size_t)b * 512 + sx0) * 1024;

    const int ar = lane & 15;
    const int ak = (lane >> 4) * 8;
    const int q  = lane >> 4;

    // ---- phase 0: S = proj @ y^T (64 x 512), split-bf16 3-term ----
    f32x4 s[4][8];
    #pragma unroll
    for (int nb = 0; nb < 4; ++nb)
        #pragma unroll
        for (int f = 0; f < 8; ++f)
            s[nb][f] = (f32x4){0.f, 0.f, 0.f, 0.f};

    const int pr = tid >> 3;
    const int pc = (tid & 7) * 4;

    for (int k0 = 0; k0 < 1024; k0 += 32) {
        __syncthreads();
        // stage proj rows (from d_out) 64x32, split
        #pragma unroll
        for (int it = 0; it < 2; ++it) {
            const int r = pr + it * 32;
            const float4 v = *(const float4*)&out[pbase + (size_t)r * 1024 + k0 + pc];
            bf16x4 h, l; cvt4(v, h, l);
            *(bf16x4*)&Ph[r][pc] = h;
            *(bf16x4*)&Pl[r][pc] = l;
        }
        #pragma unroll
        for (int nb = 0; nb < 4; ++nb) {
            if (nb) __syncthreads();   // protect Yh/Yl reuse
            const int sy0 = nb * 128;
            // stage y (128 sy x 32 k) — already k-contiguous, no transpose
            #pragma unroll
            for (int it = 0; it < 4; ++it) {
                const int r = pr + it * 32;
                const float4 v = *(const float4*)&y[ybase + (size_t)(sy0 + r) * 1024 + k0 + pc];
                bf16x4 h, l; cvt4(v, h, l);
                *(bf16x4*)&Yh[r][pc] = h;
                *(bf16x4*)&Yl[r][pc] = l;
            }
            __syncthreads();
            const bf16x8 a_h = *(const bf16x8*)&Ph[wave * 16 + ar][ak];
            const bf16x8 a_l = *(const bf16x8*)&Pl[wave * 16 + ar][ak];
            #pragma unroll
            for (int f = 0; f < 8; ++f) {
                const bf16x8 b_h = *(const bf16x8*)&Yh[f * 16 + ar][ak];
                const bf16x8 b_l = *(const bf16x8*)&Yl[f * 16 + ar][ak];
                s[nb][f] = MFMA16(a_h, b_h, s[nb][f]);
                s[nb][f] = MFMA16(a_l, b_h, s[nb][f]);
                s[nb][f] = MFMA16(a_h, b_l, s[nb][f]);
            }
        }
    }

    // ---- phase 1: row softmax (row = wave*16 + q*4 + r; cols across 16 lanes) ----
    #pragma unroll
    for (int r = 0; r < 4; ++r) {
        float m = -3.0e38f;
        #pragma unroll
        for (int nb = 0; nb < 4; ++nb)
            #pragma unroll
            for (int f = 0; f < 8; ++f)
                m = fmaxf(m, s[nb][f][r]);
        #pragma unroll
        for (int off = 1; off < 16; off <<= 1)
            m = fmaxf(m, __shfl_xor(m, off, 64));
        float sum = 0.f;
        #pragma unroll
        for (int nb = 0; nb < 4; ++nb)
            #pragma unroll
            for (int f = 0; f < 8; ++f) {
                const float e = __expf(s[nb][f][r] - m);
                s[nb][f][r] = e;
                sum += e;
            }
        #pragma unroll
        for (int off = 1; off < 16; off <<= 1)
            sum += __shfl_xor(sum, off, 64);
        const float inv = 1.0f / sum;
        #pragma unroll
        for (int nb = 0; nb < 4; ++nb)
            #pragma unroll
            for (int f = 0; f < 8; ++f)
                s[nb][f][r] *= inv;
    }
    // write P (bf16) to LDS in [m][sy] layout for A-operand reads
    #pragma unroll
    for (int nb = 0; nb < 4; ++nb)
        #pragma unroll
        for (int f = 0; f < 8; ++f)
            #pragma unroll
            for (int r = 0; r < 4; ++r)
                Pbuf[wave * 16 + q * 4 + r][nb * 128 + f * 16 + ar] = (__bf16)s[nb][f][r];

    // ---- phase 2: O = P @ y (64 x 1024), plain bf16, overwrite proj rows ----
    const int y2kb = tid >> 5;
    const int y2n4 = (tid & 31) * 4;
    for (int d0 = 0; d0 < 1024; d0 += 128) {
        f32x4 o[8];
        #pragma unroll
        for (int f = 0; f < 8; ++f) o[f] = (f32x4){0.f, 0.f, 0.f, 0.f};

        for (int k0 = 0; k0 < 512; k0 += 32) {
            __syncthreads();  // also covers Pbuf-write -> first-read ordering
            // stage y^T chunk: (32 sy x 128 d) -> Yh[d][sy], hi only
            const size_t yb = ybase + (size_t)(k0 + y2kb * 4) * 1024 + d0 + y2n4;
            const float4 v0 = *(const float4*)&y[yb];
            const float4 v1 = *(const float4*)&y[yb + 1024];
            const float4 v2 = *(const float4*)&y[yb + 2048];
            const float4 v3 = *(const float4*)&y[yb + 3072];
            const float rv[4][4] = {{v0.x, v0.y, v0.z, v0.w},
                                    {v1.x, v1.y, v1.z, v1.w},
                                    {v2.x, v2.y, v2.z, v2.w},
                                    {v3.x, v3.y, v3.z, v3.w}};
            #pragma unroll
            for (int j = 0; j < 4; ++j) {
                const bf16x4 h = (bf16x4){(__bf16)rv[0][j], (__bf16)rv[1][j],
                                          (__bf16)rv[2][j], (__bf16)rv[3][j]};
                *(bf16x4*)&Yh[y2n4 + j][y2kb * 4] = h;
            }
            __syncthreads();
            const bf16x8 a = *(const bf16x8*)&Pbuf[wave * 16 + ar][k0 + ak];
            #pragma unroll
            for (int f = 0; f < 8; ++f) {
                const bf16x8 bb = *(const bf16x8*)&Yh[f * 16 + ar][ak];
                o[f] = MFMA16(a, bb, o[f]);
            }
        }
        // write O over this block's own (already-consumed) proj rows
        #pragma unroll
        for (int f = 0; f < 8; ++f)
            #pragma unroll
            for (int r = 0; r < 4; ++r)
                out[pbase + (size_t)(wave * 16 + q * 4 + r) * 1024 + d0 + f * 16 + ar] = o[f][r];
    }
}

extern "C" void kernel_launch(void* const* d_in, const int* in_sizes, int n_in,
                              void* d_out, int out_size, void* d_ws, size_t ws_size,
                              hipStream_t stream) {
    (void)in_sizes; (void)n_in; (void)out_size; (void)d_ws; (void)ws_size;
    const float* x    = (const float*)d_in[0];
    const float* y    = (const float*)d_in[1];
    const float* W    = (const float*)d_in[2];
    const float* bias = (const float*)d_in[3];
    float* out = (float*)d_out;

    // K1: 256 m-tiles x 8 n-tiles
    proj_kernel<<<dim3(256 * 8), dim3(256), 0, stream>>>(x, W, bias, out);
    // K2: 64 batches x 8 sx-tiles
    attn_kernel<<<dim3(64 * 8), dim3(256), 0, stream>>>(y, out);
}

// Round 2
// 852.581 us; speedup vs baseline: 1.6403x; 1.6403x over previous
//
#include <hip/hip_runtime.h>

// ESIM layer: out = softmax((x@W + b) @ y^T) @ y
// B=64, Sx=Sy=512, D=1024, fp32 in/out.
//
// Fast path (needs ws >= 256 MiB):
//   prep: y->fp16 (ws), y->yT fp16 (ws), x->fp16 hi/lo (ws)
//   K1:  proj = x@W+b, 2-term fp16 MFMA, writes proj_h/proj_l fp16 into each
//        out-row's own 4KB slot (h at +0, l at +2048 bytes)
//   K2:  per (batch, 64 sx rows): S = proj@y^T (2-term fp16), softmax in regs,
//        P->LDS fp16, O = P@y via pre-transposed yT, overwrite own rows fp32.
// Fallback path (small ws): round-1 kernels (bf16 3-term), known-good.

typedef float  f32x4  __attribute__((ext_vector_type(4)));
typedef _Float16 f16x8 __attribute__((ext_vector_type(8)));
typedef _Float16 f16x4 __attribute__((ext_vector_type(4)));
typedef __bf16 bf16x8 __attribute__((ext_vector_type(8)));
typedef __bf16 bf16x4 __attribute__((ext_vector_type(4)));

#define MFMA_F16(a, b, c)  __builtin_amdgcn_mfma_f32_16x16x32_f16((a), (b), (c), 0, 0, 0)
#define MFMA_BF16(a, b, c) __builtin_amdgcn_mfma_f32_16x16x32_bf16((a), (b), (c), 0, 0, 0)

__device__ __forceinline__ void async16(const void* g, void* lds) {
    __builtin_amdgcn_global_load_lds(
        (const __attribute__((address_space(1))) unsigned int*)g,
        (__attribute__((address_space(3))) unsigned int*)lds, 16, 0, 0);
}

// ========================= prep kernels =====================================

// fp32 -> fp16 (single), grid-stride over float4
__global__ void cvt_h_kernel(const float4* __restrict__ in, f16x4* __restrict__ outp, int n4)
{
    int i = blockIdx.x * blockDim.x + threadIdx.x;
    const int stride = gridDim.x * blockDim.x;
    for (; i < n4; i += stride) {
        const float4 v = in[i];
        outp[i] = (f16x4){(_Float16)v.x, (_Float16)v.y, (_Float16)v.z, (_Float16)v.w};
    }
}

// fp32 -> fp16 hi + lo residual
__global__ void cvt_hl_kernel(const float4* __restrict__ in, f16x4* __restrict__ oh,
                              f16x4* __restrict__ ol, int n4)
{
    int i = blockIdx.x * blockDim.x + threadIdx.x;
    const int stride = gridDim.x * blockDim.x;
    for (; i < n4; i += stride) {
        const float4 v = in[i];
        const _Float16 h0 = (_Float16)v.x, h1 = (_Float16)v.y,
                       h2 = (_Float16)v.z, h3 = (_Float16)v.w;
        oh[i] = (f16x4){h0, h1, h2, h3};
        ol[i] = (f16x4){(_Float16)(v.x - (float)h0), (_Float16)(v.y - (float)h1),
                        (_Float16)(v.z - (float)h2), (_Float16)(v.w - (float)h3)};
    }
}

// y_f16 [b][sy][d] -> yT_f16 [b][d][sy], 64x64 tiles via LDS
__global__ void transp_y_kernel(const _Float16* __restrict__ yf, _Float16* __restrict__ yT)
{
    __shared__ _Float16 LT[64][72];
    const int tid = threadIdx.x;
    const int b   = blockIdx.x >> 7;
    const int rem = blockIdx.x & 127;
    const int sy0 = (rem >> 4) * 64;   // 8 sy tiles
    const int d0  = (rem & 15) * 64;   // 16 d tiles
    const int r0 = tid >> 4;
    const int c4 = (tid & 15) * 4;
    #pragma unroll
    for (int i = 0; i < 4; ++i) {
        const int r = r0 + i * 16;
        const f16x4 v = *(const f16x4*)&yf[((size_t)b * 512 + sy0 + r) * 1024 + d0 + c4];
        #pragma unroll
        for (int cc = 0; cc < 4; ++cc) {
            const int c = (cc + (tid & 3)) & 3;   // swizzle to spread LDS banks
            LT[c4 + c][r] = v[c];
        }
    }
    __syncthreads();
    #pragma unroll
    for (int i = 0; i < 4; ++i) {
        const int dr = r0 + i * 16;
        const f16x4 v = *(const f16x4*)&LT[dr][(tid & 15) * 4];
        *(f16x4*)&yT[((size_t)b * 1024 + d0 + dr) * 512 + sy0 + (tid & 15) * 4] = v;
    }
}

// ===================== K1: proj = x@W + b (fp16 2-term) =====================
// M=32768, N=1024, K=1024. 128x128 tile, BK=32, 4 waves (2x2 of 64x64).
// Writes proj_h fp16 at row-byte +0, proj_l fp16 at row-byte +2048 (own slot).
__global__ __launch_bounds__(256, 3)
void proj_f16_kernel(const _Float16* __restrict__ xh, const _Float16* __restrict__ xl,
                     const float* __restrict__ W, const float* __restrict__ bias,
                     char* __restrict__ outc)
{
    __shared__ _Float16 Xh[128][32];
    __shared__ _Float16 Xl[128][32];
    __shared__ _Float16 Wf[128][32];   // [n][k], W transposed+cvt at staging

    const int tid = threadIdx.x, lane = tid & 63, wave = tid >> 6;
    const int m0 = (blockIdx.x >> 3) * 128, n0 = (blockIdx.x & 7) * 128;
    const int wm = (wave >> 1) * 64, wn = (wave & 1) * 64;
    const int ar = lane & 15, qk = (lane >> 4) * 8;

    f32x4 acc[4][4];
    #pragma unroll
    for (int i = 0; i < 4; ++i)
        #pragma unroll
        for (int j = 0; j < 4; ++j)
            acc[i][j] = (f32x4){0.f, 0.f, 0.f, 0.f};

    const int wkb = tid >> 5, wn4 = (tid & 31) * 4;
    const int lrow = lane >> 2, lcol = (lane & 3) * 8;

    for (int k0 = 0; k0 < 1024; k0 += 32) {
        __syncthreads();
        #pragma unroll
        for (int t = 0; t < 2; ++t) {
            const int r = wave * 32 + t * 16 + lrow;
            async16(&xh[(size_t)(m0 + r) * 1024 + k0 + lcol], &Xh[wave * 32 + t * 16][0]);
            async16(&xl[(size_t)(m0 + r) * 1024 + k0 + lcol], &Xl[wave * 32 + t * 16][0]);
        }
        {   // W tile (32k x 128n) -> Wf[n][k], fp32->fp16
            const size_t wb = (size_t)(k0 + wkb * 4) * 1024 + n0 + wn4;
            const float4 v0 = *(const float4*)&W[wb];
            const float4 v1 = *(const float4*)&W[wb + 1024];
            const float4 v2 = *(const float4*)&W[wb + 2048];
            const float4 v3 = *(const float4*)&W[wb + 3072];
            const float rv[4][4] = {{v0.x, v0.y, v0.z, v0.w},
                                    {v1.x, v1.y, v1.z, v1.w},
                                    {v2.x, v2.y, v2.z, v2.w},
                                    {v3.x, v3.y, v3.z, v3.w}};
            #pragma unroll
            for (int j = 0; j < 4; ++j) {
                const f16x4 hv = {(_Float16)rv[0][j], (_Float16)rv[1][j],
                                  (_Float16)rv[2][j], (_Float16)rv[3][j]};
                *(f16x4*)&Wf[wn4 + j][wkb * 4] = hv;
            }
        }
        __syncthreads();

        f16x8 ah[4], al[4], bf[4];
        #pragma unroll
        for (int f = 0; f < 4; ++f) {
            ah[f] = *(const f16x8*)&Xh[wm + f * 16 + ar][qk];
            al[f] = *(const f16x8*)&Xl[wm + f * 16 + ar][qk];
            bf[f] = *(const f16x8*)&Wf[wn + f * 16 + ar][qk];
        }
        #pragma unroll
        for (int i = 0; i < 4; ++i)
            #pragma unroll
            for (int j = 0; j < 4; ++j) {
                acc[i][j] = MFMA_F16(ah[i], bf[j], acc[i][j]);
                acc[i][j] = MFMA_F16(al[i], bf[j], acc[i][j]);
            }
    }

    // epilogue: +bias, split h/l fp16 into own row slot
    const int q4 = (lane >> 4) * 4;
    #pragma unroll
    for (int j = 0; j < 4; ++j) {
        const int n = n0 + wn + j * 16 + ar;
        const float bv = bias[n];
        #pragma unroll
        for (int i = 0; i < 4; ++i)
            #pragma unroll
            for (int r = 0; r < 4; ++r) {
                const int R = m0 + wm + i * 16 + q4 + r;
                const float v = acc[i][j][r] + bv;
                const _Float16 h = (_Float16)v;
                const _Float16 l = (_Float16)(v - (float)h);
                _Float16* rowp = (_Float16*)(outc + (size_t)R * 4096);
                rowp[n] = h;
                rowp[1024 + n] = l;
            }
    }
}

// ================= K2: attention per (batch, 64 sx rows), fp16 ==============
__global__ __launch_bounds__(256, 2)
void attn_f16_kernel(const _Float16* __restrict__ yf, const _Float16* __restrict__ yT,
                     char* __restrict__ outc)
{
    __shared__ __align__(16) char smem[73728];
    _Float16 (*Yst)[32]  = (_Float16(*)[32])smem;            // [512][32] phase 0
    _Float16 (*Pbuf)[512] = (_Float16(*)[512])smem;          // [64][512] phase 1/2
    _Float16 (*Yt)[32]   = (_Float16(*)[32])(smem + 65536);  // [128][32] phase 2

    const int tid = threadIdx.x, lane = tid & 63, wave = tid >> 6;
    const int b = blockIdx.x >> 3, sx0 = (blockIdx.x & 7) * 64;
    const int pbase = b * 512 + sx0;
    const int ar = lane & 15, q = lane >> 4, qk = q * 8;
    const int lrow = lane >> 2, lcol = (lane & 3) * 8;
    const size_t ybase = (size_t)b * 512 * 1024;

    // ---- phase 0: S = proj @ y^T (64 x 512), 2-term fp16 ----
    f32x4 s[32];
    #pragma unroll
    for (int t = 0; t < 32; ++t) s[t] = (f32x4){0.f, 0.f, 0.f, 0.f};

    const _Float16* prow = (const _Float16*)(outc + (size_t)(pbase + wave * 16 + ar) * 4096);

    for (int k0 = 0; k0 < 1024; k0 += 32) {
        __syncthreads();
        #pragma unroll
        for (int t = 0; t < 8; ++t) {   // stage all 512 sy rows, 32 k each
            const int r = wave * 128 + t * 16 + lrow;
            async16(&yf[ybase + (size_t)r * 1024 + k0 + lcol], &Yst[wave * 128 + t * 16][0]);
        }
        // A-fragments direct from global (L2-hot own proj rows)
        const f16x8 a_h = *(const f16x8*)(prow + k0 + qk);
        const f16x8 a_l = *(const f16x8*)(prow + 1024 + k0 + qk);
        __syncthreads();
        #pragma unroll
        for (int t = 0; t < 32; ++t) {
            const f16x8 bfrag = *(const f16x8*)&Yst[t * 16 + ar][qk];
            s[t] = MFMA_F16(a_h, bfrag, s[t]);
            s[t] = MFMA_F16(a_l, bfrag, s[t]);
        }
    }

    // ---- phase 1: row softmax (row = wave*16 + q*4 + r; cols over 16 lanes) ----
    #pragma unroll
    for (int r = 0; r < 4; ++r) {
        float m = -3.0e38f;
        #pragma unroll
        for (int t = 0; t < 32; ++t) m = fmaxf(m, s[t][r]);
        #pragma unroll
        for (int off = 1; off < 16; off <<= 1) m = fmaxf(m, __shfl_xor(m, off, 64));
        float sum = 0.f;
        #pragma unroll
        for (int t = 0; t < 32; ++t) {
            const float e = __expf(s[t][r] - m);
            s[t][r] = e;
            sum += e;
        }
        #pragma unroll
        for (int off = 1; off < 16; off <<= 1) sum += __shfl_xor(sum, off, 64);
        const float inv = 1.0f / sum;
        #pragma unroll
        for (int t = 0; t < 32; ++t) s[t][r] *= inv;
    }

    __syncthreads();   // Yst dead everywhere before Pbuf overwrite
    #pragma unroll
    for (int t = 0; t < 32; ++t)
        #pragma unroll
        for (int r = 0; r < 4; ++r)
            Pbuf[wave * 16 + q * 4 + r][t * 16 + ar] = (_Float16)s[t][r];

    // ---- phase 2: O = P @ y via yT, d-chunks of 128 ----
    float* outF = (float*)outc;
    for (int dc = 0; dc < 8; ++dc) {
        f32x4 o[8];
        #pragma unroll
        for (int t = 0; t < 8; ++t) o[t] = (f32x4){0.f, 0.f, 0.f, 0.f};

        for (int k0 = 0; k0 < 512; k0 += 32) {
            __syncthreads();
            #pragma unroll
            for (int t = 0; t < 2; ++t) {   // stage yT[dc*128 .. +128][k0 .. +32]
                const int r = wave * 32 + t * 16 + lrow;
                async16(&yT[(size_t)(b * 1024 + dc * 128 + r) * 512 + k0 + lcol],
                        &Yt[wave * 32 + t * 16][0]);
            }
            const f16x8 a = *(const f16x8*)&Pbuf[wave * 16 + ar][k0 + qk];
            __syncthreads();
            #pragma unroll
            for (int t = 0; t < 8; ++t) {
                const f16x8 bfrag = *(const f16x8*)&Yt[t * 16 + ar][qk];
                o[t] = MFMA_F16(a, bfrag, o[t]);
            }
        }
        #pragma unroll
        for (int t = 0; t < 8; ++t)
            #pragma unroll
            for (int r = 0; r < 4; ++r)
                outF[(size_t)(pbase + wave * 16 + q * 4 + r) * 1024 + dc * 128 + t * 16 + ar]
                    = o[t][r];
    }
}

// ===================== fallback path (round-1, known good) ==================

__device__ __forceinline__ void cvt4(const float4 v, bf16x4& h, bf16x4& l) {
    const float f0 = v.x, f1 = v.y, f2 = v.z, f3 = v.w;
    const __bf16 h0 = (__bf16)f0, h1 = (__bf16)f1, h2 = (__bf16)f2, h3 = (__bf16)f3;
    h = (bf16x4){h0, h1, h2, h3};
    l = (bf16x4){(__bf16)(f0 - (float)h0), (__bf16)(f1 - (float)h1),
                 (__bf16)(f2 - (float)h2), (__bf16)(f3 - (float)h3)};
}

__global__ __launch_bounds__(256, 2)
void proj_kernel_fb(const float* __restrict__ x, const float* __restrict__ W,
                    const float* __restrict__ bias, float* __restrict__ proj)
{
    __shared__ __bf16 Ah[128][40];
    __shared__ __bf16 Al[128][40];
    __shared__ __bf16 Bh[128][40];
    __shared__ __bf16 Bl[128][40];

    const int tid = threadIdx.x, lane = tid & 63, wave = tid >> 6;
    const int wm = (wave >> 1) * 64, wn = (wave & 1) * 64;
    const int m0 = (blockIdx.x >> 3) * 128, n0 = (blockIdx.x & 7) * 128;
    const int ar = lane & 15, ak = (lane >> 4) * 8;

    f32x4 acc[4][4];
    #pragma unroll
    for (int i = 0; i < 4; ++i)
        #pragma unroll
        for (int j = 0; j < 4; ++j)
            acc[i][j] = (f32x4){0.f, 0.f, 0.f, 0.f};

    const int xr = tid >> 3, xc = (tid & 7) * 4;
    const int wkb = tid >> 5, wn4 = (tid & 31) * 4;

    for (int k0 = 0; k0 < 1024; k0 += 32) {
        __syncthreads();
        #pragma unroll
        for (int it = 0; it < 4; ++it) {
            const int r = xr + it * 32;
            const float4 v = *(const float4*)&x[(size_t)(m0 + r) * 1024 + k0 + xc];
            bf16x4 h, l; cvt4(v, h, l);
            *(bf16x4*)&Ah[r][xc] = h;
            *(bf16x4*)&Al[r][xc] = l;
        }
        {
            const size_t wb = (size_t)(k0 + wkb * 4) * 1024 + n0 + wn4;
            const float4 v0 = *(const float4*)&W[wb];
            const float4 v1 = *(const float4*)&W[wb + 1024];
            const float4 v2 = *(const float4*)&W[wb + 2048];
            const float4 v3 = *(const float4*)&W[wb + 3072];
            const float rv[4][4] = {{v0.x, v0.y, v0.z, v0.w},
                                    {v1.x, v1.y, v1.z, v1.w},
                                    {v2.x, v2.y, v2.z, v2.w},
                                    {v3.x, v3.y, v3.z, v3.w}};
            #pragma unroll
            for (int j = 0; j < 4; ++j) {
                bf16x4 h, l;
                #pragma unroll
                for (int kk = 0; kk < 4; ++kk) {
                    const float f = rv[kk][j];
                    const __bf16 hb = (__bf16)f;
                    h[kk] = hb;
                    l[kk] = (__bf16)(f - (float)hb);
                }
                *(bf16x4*)&Bh[wn4 + j][wkb * 4] = h;
                *(bf16x4*)&Bl[wn4 + j][wkb * 4] = l;
            }
        }
        __syncthreads();

        bf16x8 a_h[4], a_l[4], b_h[4], b_l[4];
        #pragma unroll
        for (int f = 0; f < 4; ++f) {
            a_h[f] = *(const bf16x8*)&Ah[wm + f * 16 + ar][ak];
            a_l[f] = *(const bf16x8*)&Al[wm + f * 16 + ar][ak];
            b_h[f] = *(const bf16x8*)&Bh[wn + f * 16 + ar][ak];
            b_l[f] = *(const bf16x8*)&Bl[wn + f * 16 + ar][ak];
        }
        #pragma unroll
        for (int i = 0; i < 4; ++i)
            #pragma unroll
            for (int j = 0; j < 4; ++j) {
                acc[i][j] = MFMA_BF16(a_h[i], b_h[j], acc[i][j]);
                acc[i][j] = MFMA_BF16(a_l[i], b_h[j], acc[i][j]);
                acc[i][j] = MFMA_BF16(a_h[i], b_l[j], acc[i][j]);
            }
    }

    const int q4 = (lane >> 4) * 4;
    #pragma unroll
    for (int j = 0; j < 4; ++j) {
        const int n = n0 + wn + j * 16 + ar;
        const float bv = bias[n];
        #pragma unroll
        for (int i = 0; i < 4; ++i) {
            const size_t base = (size_t)(m0 + wm + i * 16 + q4) * 1024 + n;
            #pragma unroll
            for (int r = 0; r < 4; ++r)
                proj[base + (size_t)r * 1024] = acc[i][j][r] + bv;
        }
    }
}

__global__ __launch_bounds__(256, 1)
void attn_kernel_fb(const float* __restrict__ y, float* __restrict__ out)
{
    __shared__ __bf16 Ph[64][40];
    __shared__ __bf16 Pl[64][40];
    __shared__ __bf16 Yh[128][40];
    __shared__ __bf16 Yl[128][40];
    __shared__ __bf16 Pbuf[64][520];

    const int tid = threadIdx.x, lane = tid & 63, wave = tid >> 6;
    const int b = blockIdx.x >> 3, sx0 = (blockIdx.x & 7) * 64;
    const size_t ybase = (size_t)b * 512 * 1024;
    const size_t pbase = ((size_t)b * 512 + sx0) * 1024;
    const int ar = lane & 15, ak = (lane >> 4) * 8, q = lane >> 4;

    f32x4 s[4][8];
    #pragma unroll
    for (int nb = 0; nb < 4; ++nb)
        #pragma unroll
        for (int f = 0; f < 8; ++f)
            s[nb][f] = (f32x4){0.f, 0.f, 0.f, 0.f};

    const int pr = tid >> 3, pc = (tid & 7) * 4;

    for (int k0 = 0; k0 < 1024; k0 += 32) {
        __syncthreads();
        #pragma unroll
        for (int it = 0; it < 2; ++it) {
            const int r = pr + it * 32;
            const float4 v = *(const float4*)&out[pbase + (size_t)r * 1024 + k0 + pc];
            bf16x4 h, l; cvt4(v, h, l);
            *(bf16x4*)&Ph[r][pc] = h;
            *(bf16x4*)&Pl[r][pc] = l;
        }
        #pragma unroll
        for (int nb = 0; nb < 4; ++nb) {
            if (nb) __syncthreads();
            const int sy0 = nb * 128;
            #pragma unroll
            for (int it = 0; it < 4; ++it) {
                const int r = pr + it * 32;
                const float4 v = *(const float4*)&y[ybase + (size_t)(sy0 + r) * 1024 + k0 + pc];
                bf16x4 h, l; cvt4(v, h, l);
                *(bf16x4*)&Yh[r][pc] = h;
                *(bf16x4*)&Yl[r][pc] = l;
            }
            __syncthreads();
            const bf16x8 a_h = *(const bf16x8*)&Ph[wave * 16 + ar][ak];
            const bf16x8 a_l = *(const bf16x8*)&Pl[wave * 16 + ar][ak];
            #pragma unroll
            for (int f = 0; f < 8; ++f) {
                const bf16x8 b_h = *(const bf16x8*)&Yh[f * 16 + ar][ak];
                const bf16x8 b_l = *(const bf16x8*)&Yl[f * 16 + ar][ak];
                s[nb][f] = MFMA_BF16(a_h, b_h, s[nb][f]);
                s[nb][f] = MFMA_BF16(a_l, b_h, s[nb][f]);
                s[nb][f] = MFMA_BF16(a_h, b_l, s[nb][f]);
            }
        }
    }

    #pragma unroll
    for (int r = 0; r < 4; ++r) {
        float m = -3.0e38f;
        #pragma unroll
        for (int nb = 0; nb < 4; ++nb)
            #pragma unroll
            for (int f = 0; f < 8; ++f)
                m = fmaxf(m, s[nb][f][r]);
        #pragma unroll
        for (int off = 1; off < 16; off <<= 1)
            m = fmaxf(m, __shfl_xor(m, off, 64));
        float sum = 0.f;
        #pragma unroll
        for (int nb = 0; nb < 4; ++nb)
            #pragma unroll
            for (int f = 0; f < 8; ++f) {
                const float e = __expf(s[nb][f][r] - m);
                s[nb][f][r] = e;
                sum += e;
            }
        #pragma unroll
        for (int off = 1; off < 16; off <<= 1)
            sum += __shfl_xor(sum, off, 64);
        const float inv = 1.0f / sum;
        #pragma unroll
        for (int nb = 0; nb < 4; ++nb)
            #pragma unroll
            for (int f = 0; f < 8; ++f)
                s[nb][f][r] *= inv;
    }
    #pragma unroll
    for (int nb = 0; nb < 4; ++nb)
        #pragma unroll
        for (int f = 0; f < 8; ++f)
            #pragma unroll
            for (int r = 0; r < 4; ++r)
                Pbuf[wave * 16 + q * 4 + r][nb * 128 + f * 16 + ar] = (__bf16)s[nb][f][r];

    const int y2kb = tid >> 5, y2n4 = (tid & 31) * 4;
    for (int d0 = 0; d0 < 1024; d0 += 128) {
        f32x4 o[8];
        #pragma unroll
        for (int f = 0; f < 8; ++f) o[f] = (f32x4){0.f, 0.f, 0.f, 0.f};

        for (int k0 = 0; k0 < 512; k0 += 32) {
            __syncthreads();
            const size_t yb = ybase + (size_t)(k0 + y2kb * 4) * 1024 + d0 + y2n4;
            const float4 v0 = *(const float4*)&y[yb];
            const float4 v1 = *(const float4*)&y[yb + 1024];
            const float4 v2 = *(const float4*)&y[yb + 2048];
            const float4 v3 = *(const float4*)&y[yb + 3072];
            const float rv[4][4] = {{v0.x, v0.y, v0.z, v0.w},
                                    {v1.x, v1.y, v1.z, v1.w},
                                    {v2.x, v2.y, v2.z, v2.w},
                                    {v3.x, v3.y, v3.z, v3.w}};
            #pragma unroll
            for (int j = 0; j < 4; ++j) {
                const bf16x4 h = (bf16x4){(__bf16)rv[0][j], (__bf16)rv[1][j],
                                          (__bf16)rv[2][j], (__bf16)rv[3][j]};
                *(bf16x4*)&Yh[y2n4 + j][y2kb * 4] = h;
            }
            __syncthreads();
            const bf16x8 a = *(const bf16x8*)&Pbuf[wave * 16 + ar][k0 + ak];
            #pragma unroll
            for (int f = 0; f < 8; ++f) {
                const bf16x8 bb = *(const bf16x8*)&Yh[f * 16 + ar][ak];
                o[f] = MFMA_BF16(a, bb, o[f]);
            }
        }
        #pragma unroll
        for (int f = 0; f < 8; ++f)
            #pragma unroll
            for (int r = 0; r < 4; ++r)
                out[pbase + (size_t)(wave * 16 + q * 4 + r) * 1024 + d0 + f * 16 + ar] = o[f][r];
    }
}

// ============================== launch ======================================

extern "C" void kernel_launch(void* const* d_in, const int* in_sizes, int n_in,
                              void* d_out, int out_size, void* d_ws, size_t ws_size,
                              hipStream_t stream) {
    (void)in_sizes; (void)n_in; (void)out_size;
    const float* x    = (const float*)d_in[0];
    const float* y    = (const float*)d_in[1];
    const float* W    = (const float*)d_in[2];
    const float* bias = (const float*)d_in[3];

    if (ws_size >= 268435456ULL) {
        // ws layout (fp16 elements): y_f16 | yT_f16 | x_h | x_l, 67.1 MB each
        _Float16* yf = (_Float16*)d_ws;
        _Float16* yT = yf + 33554432;
        _Float16* xh = yT + 33554432;
        _Float16* xl = xh + 33554432;
        cvt_h_kernel<<<dim3(2048), dim3(256), 0, stream>>>((const float4*)y, (f16x4*)yf, 8388608);
        cvt_hl_kernel<<<dim3(2048), dim3(256), 0, stream>>>((const float4*)x, (f16x4*)xh,
                                                            (f16x4*)xl, 8388608);
        transp_y_kernel<<<dim3(8192), dim3(256), 0, stream>>>(yf, yT);
        proj_f16_kernel<<<dim3(2048), dim3(256), 0, stream>>>(xh, xl, W, bias, (char*)d_out);
        attn_f16_kernel<<<dim3(512), dim3(256), 0, stream>>>(yf, yT, (char*)d_out);
    } else {
        float* out = (float*)d_out;
        proj_kernel_fb<<<dim3(256 * 8), dim3(256), 0, stream>>>(x, W, bias, out);
        attn_kernel_fb<<<dim3(64 * 8), dim3(256), 0, stream>>>(y, out);
    }
}